// Round 1
// baseline (248.367 us; speedup 1.0000x reference)
//
#include <hip/hip_runtime.h>

typedef unsigned short u16;
typedef __bf16 bf16x8 __attribute__((ext_vector_type(8)));
typedef float f32x4 __attribute__((ext_vector_type(4)));

__device__ __forceinline__ u16 f2bf(float f) {
  union { float f; unsigned int u; } v; v.f = f;
  unsigned int r = v.u + 0x7fffu + ((v.u >> 16) & 1u);
  return (u16)(r >> 16);
}

__device__ __forceinline__ f32x4 mfma16(bf16x8 a, bf16x8 b, f32x4 c) {
  return __builtin_amdgcn_mfma_f32_16x16x32_bf16(a, b, c, 0, 0, 0);
}

__device__ __forceinline__ void async16(void* lds, const void* g) {
  __builtin_amdgcn_global_load_lds(
      (const __attribute__((address_space(1))) unsigned int*)g,
      (__attribute__((address_space(3))) unsigned int*)lds, 16, 0, 0);
}

// ---------------------------------------------------------------- prep: casts
// Wq (x0.125 scale-fold), Wkv, Wout, context  -> bf16
__global__ __launch_bounds__(256) void prep_cast(
    const float* __restrict__ Wq, const float* __restrict__ Wkv,
    const float* __restrict__ Wout, const float* __restrict__ ctx,
    u16* __restrict__ Wq_b, u16* __restrict__ Wkv_b,
    u16* __restrict__ Wout_b, u16* __restrict__ ctx_b) {
  const long NWQ = 512L * 512, NWKV = 1024L * 768, NWOUT = 512L * 512, NCTX = 2048L * 768;
  const long total = NWQ + NWKV + NWOUT + NCTX;
  long stride = (long)gridDim.x * 256;
  for (long i = (long)blockIdx.x * 256 + threadIdx.x; i < total; i += stride) {
    long j = i;
    if (j < NWQ) { Wq_b[j] = f2bf(Wq[j] * 0.125f); continue; }
    j -= NWQ;
    if (j < NWKV) { Wkv_b[j] = f2bf(Wkv[j]); continue; }
    j -= NWKV;
    if (j < NWOUT) { Wout_b[j] = f2bf(Wout[j]); continue; }
    j -= NWOUT;
    ctx_b[j] = f2bf(ctx[j]);
  }
}

// ------------------------------------------------- transpose x -> xT bf16
// x [8][512][4096] f32  ->  xT [8][4096][512] bf16
__global__ __launch_bounds__(256) void transpose_x(const float* __restrict__ x,
                                                   u16* __restrict__ xT) {
  __shared__ float tile[64][65];
  const int b = blockIdx.z, p0 = blockIdx.x * 64, c0 = blockIdx.y * 64;
  const int tx = threadIdx.x & 63, ty = threadIdx.x >> 6;
  const float* xb = x + (long)b * (512L * 4096);
  #pragma unroll
  for (int i = ty; i < 64; i += 4)
    tile[i][tx] = xb[(long)(c0 + i) * 4096 + p0 + tx];
  __syncthreads();
  u16* xTb = xT + (long)b * (4096L * 512);
  #pragma unroll
  for (int i = ty; i < 64; i += 4)
    xTb[(long)(p0 + i) * 512 + c0 + tx] = f2bf(tile[tx][i]);
}

// ------------------------------------------------- transpose v -> vT bf16
// kv [2048][1024] bf16 (v = cols 512..1023) -> vT [8][512][256]
__global__ __launch_bounds__(256) void transpose_v(const u16* __restrict__ kv,
                                                   u16* __restrict__ vT) {
  __shared__ u16 tile[64][65];
  const int b = blockIdx.z, e0 = blockIdx.x * 64, n0 = blockIdx.y * 64;
  const int tx = threadIdx.x & 63, ty = threadIdx.x >> 6;
  #pragma unroll
  for (int i = ty; i < 64; i += 4)
    tile[i][tx] = kv[(long)(b * 256 + n0 + i) * 1024 + 512 + e0 + tx];
  __syncthreads();
  #pragma unroll
  for (int i = ty; i < 64; i += 4)
    vT[(long)b * (512L * 256) + (long)(e0 + i) * 256 + n0 + tx] = tile[tx][i];
}

// ---------------------------------------------------------------- NT GEMM
// C[M][N] = A[M][K] . B[N][K]^T, A/B bf16 K-contiguous. 128x128 tile, 4 waves,
// BK=32, double-buffered global_load_lds (width 16), 1 barrier per K-step.
// EPI 0: store bf16.  EPI 1: fp32 store + bias[row] + resid (same layout as C).
template <int EPI>
__global__ __launch_bounds__(256) void gemm_nt(
    const u16* __restrict__ A, const u16* __restrict__ B, void* __restrict__ Cv,
    int M, int N, int K, long aStrideZ, long bStrideZ, long cStrideZ,
    const float* __restrict__ bias, const float* __restrict__ resid) {
  __shared__ u16 ldsA[2][128 * 32];
  __shared__ u16 ldsB[2][128 * 32];
  const int t = threadIdx.x, wv = t >> 6, ln = t & 63;
  const int m0 = blockIdx.x * 128, n0 = blockIdx.y * 128, z = blockIdx.z;
  const u16* Az = A + (long)z * aStrideZ;
  const u16* Bz = B + (long)z * bStrideZ;
  const int wr = wv >> 1, wc = wv & 1, fr = ln & 15, fq = ln >> 4;

  const u16* aSrc[2];
  const u16* bSrc[2];
  int lbase[2];
  #pragma unroll
  for (int i = 0; i < 2; i++) {
    int c = wv * 64 + ln + i * 256;       // chunk id: row = c>>2, part = c&3
    aSrc[i] = Az + (long)(m0 + (c >> 2)) * K + (c & 3) * 8;
    bSrc[i] = Bz + (long)(n0 + (c >> 2)) * K + (c & 3) * 8;
    lbase[i] = (wv * 64 + i * 256) * 8;   // elements; HW adds lane*16B
  }

  f32x4 acc[4][4] = {};
  const int nk = K >> 5;
  int cur = 0;

  #pragma unroll
  for (int i = 0; i < 2; i++) {
    async16(&ldsA[0][lbase[i]], aSrc[i]);
    async16(&ldsB[0][lbase[i]], bSrc[i]);
  }

  for (int kt = 0; kt < nk; ++kt) {
    __syncthreads();  // compiler drains vmcnt/lgkmcnt before barrier
    if (kt + 1 < nk) {
      const int ko = (kt + 1) * 32;
      #pragma unroll
      for (int i = 0; i < 2; i++) {
        async16(&ldsA[cur ^ 1][lbase[i]], aSrc[i] + ko);
        async16(&ldsB[cur ^ 1][lbase[i]], bSrc[i] + ko);
      }
    }
    bf16x8 a[4], b[4];
    #pragma unroll
    for (int mf = 0; mf < 4; ++mf)
      a[mf] = *(const bf16x8*)&ldsA[cur][(wr * 64 + mf * 16 + fr) * 32 + fq * 8];
    #pragma unroll
    for (int nf = 0; nf < 4; ++nf)
      b[nf] = *(const bf16x8*)&ldsB[cur][(wc * 64 + nf * 16 + fr) * 32 + fq * 8];
    #pragma unroll
    for (int mf = 0; mf < 4; ++mf)
      #pragma unroll
      for (int nf = 0; nf < 4; ++nf)
        acc[mf][nf] = mfma16(a[mf], b[nf], acc[mf][nf]);
    cur ^= 1;
  }

  if (EPI == 0) {
    u16* Cb = (u16*)Cv + (long)z * cStrideZ;
    #pragma unroll
    for (int mf = 0; mf < 4; ++mf)
      #pragma unroll
      for (int r = 0; r < 4; ++r) {
        int grow = m0 + wr * 64 + mf * 16 + fq * 4 + r;
        #pragma unroll
        for (int nf = 0; nf < 4; ++nf) {
          int gcol = n0 + wc * 64 + nf * 16 + fr;
          Cb[(long)grow * N + gcol] = f2bf(acc[mf][nf][r]);
        }
      }
  } else {
    float* Cf = (float*)Cv + (long)z * cStrideZ;
    const float* Rz = resid + (long)z * cStrideZ;
    #pragma unroll
    for (int mf = 0; mf < 4; ++mf)
      #pragma unroll
      for (int r = 0; r < 4; ++r) {
        int grow = m0 + wr * 64 + mf * 16 + fq * 4 + r;
        float bv = bias[grow];
        #pragma unroll
        for (int nf = 0; nf < 4; ++nf) {
          int gcol = n0 + wc * 64 + nf * 16 + fr;
          long idx = (long)grow * N + gcol;
          Cf[idx] = acc[mf][nf][r] + bv + Rz[idx];
        }
      }
  }
}

// ---------------------------------------------------------------- attention
// q [b][4096][512], kv [b*256][1024] (k cols 0..511), vT [b][512][256]
// -> ao [b][4096][512].  Block: 64 q-rows, 4 waves x 16 rows, full n=256.
// K/V frags straight from global (L2-resident). P via XOR-swizzled LDS.
__global__ __launch_bounds__(256) void attn_kernel(
    const u16* __restrict__ q, const u16* __restrict__ kv,
    const u16* __restrict__ vT, u16* __restrict__ ao) {
  __shared__ u16 plds[64 * 256];
  const int t = threadIdx.x, w = t >> 6, ln = t & 63;
  const int fr = ln & 15, fq = ln >> 4;
  const int p0 = blockIdx.x * 64, h = blockIdx.y, b = blockIdx.z;

  // Q fragments (A-operand): row p = p0 + w*16 + fr, k = d
  const u16* qb = q + ((long)b * 4096 + p0 + w * 16 + fr) * 512 + h * 64;
  bf16x8 qf[2];
  #pragma unroll
  for (int kk = 0; kk < 2; ++kk)
    qf[kk] = *(const bf16x8*)&qb[kk * 32 + fq * 8];

  // S = Q.K^T  (s[nf]: cols nf*16+fr, rows w*16 + fq*4 + r)
  const u16* kb = kv + (long)b * 256 * 1024 + h * 64;
  f32x4 s[16] = {};
  #pragma unroll
  for (int nf = 0; nf < 16; ++nf) {
    #pragma unroll
    for (int kk = 0; kk < 2; ++kk) {
      bf16x8 kf = *(const bf16x8*)&kb[(long)(nf * 16 + fr) * 1024 + kk * 32 + fq * 8];
      s[nf] = mfma16(qf[kk], kf, s[nf]);
    }
  }

  // softmax over 256 cols per row; row lives across the 16-lane column group
  char* praw = (char*)plds;
  #pragma unroll
  for (int r = 0; r < 4; ++r) {
    float m = -3.0e38f;
    #pragma unroll
    for (int nf = 0; nf < 16; ++nf) m = fmaxf(m, s[nf][r]);
    m = fmaxf(m, __shfl_xor(m, 1));
    m = fmaxf(m, __shfl_xor(m, 2));
    m = fmaxf(m, __shfl_xor(m, 4));
    m = fmaxf(m, __shfl_xor(m, 8));
    float sum = 0.f;
    #pragma unroll
    for (int nf = 0; nf < 16; ++nf) {
      float e = __expf(s[nf][r] - m);
      s[nf][r] = e;
      sum += e;
    }
    sum += __shfl_xor(sum, 1);
    sum += __shfl_xor(sum, 2);
    sum += __shfl_xor(sum, 4);
    sum += __shfl_xor(sum, 8);
    float inv = 1.0f / sum;
    int prow = w * 16 + fq * 4 + r;
    #pragma unroll
    for (int nf = 0; nf < 16; ++nf) {
      int pcol = nf * 16 + fr;
      *(u16*)(praw + prow * 512 + ((pcol * 2) ^ ((prow & 7) << 4))) =
          f2bf(s[nf][r] * inv);
    }
  }
  asm volatile("s_waitcnt lgkmcnt(0)" ::: "memory");  // P writes -> P reads (same wave)

  // O = P.V  via vT (NT): o cols d = nfd*16+fr, rows w*16 + fq*4 + r
  const u16* vb = vT + (long)b * (512L * 256) + (long)h * 64 * 256;
  f32x4 o[4] = {};
  const int prowA = w * 16 + fr;
  #pragma unroll
  for (int kk2 = 0; kk2 < 8; ++kk2) {
    bf16x8 pf = *(const bf16x8*)(praw + prowA * 512 +
                                 ((kk2 * 64 + fq * 16) ^ ((prowA & 7) << 4)));
    #pragma unroll
    for (int nfd = 0; nfd < 4; ++nfd) {
      int dd = nfd * 16 + fr;
      bf16x8 vf = *(const bf16x8*)&vb[(long)dd * 256 + kk2 * 32 + fq * 8];
      o[nfd] = mfma16(pf, vf, o[nfd]);
    }
  }

  u16* aob = ao + ((long)b * 4096 + p0 + w * 16) * 512 + h * 64;
  #pragma unroll
  for (int nfd = 0; nfd < 4; ++nfd)
    #pragma unroll
    for (int r = 0; r < 4; ++r)
      aob[(long)(fq * 4 + r) * 512 + nfd * 16 + fr] = f2bf(o[nfd][r]);
}

// ---------------------------------------------------------------- launch
extern "C" void kernel_launch(void* const* d_in, const int* in_sizes, int n_in,
                              void* d_out, int out_size, void* d_ws, size_t ws_size,
                              hipStream_t stream) {
  const float* x    = (const float*)d_in[0];
  const float* ctx  = (const float*)d_in[1];
  const float* Wq   = (const float*)d_in[2];
  const float* Wkv  = (const float*)d_in[3];
  const float* Wout = (const float*)d_in[4];
  const float* bout = (const float*)d_in[5];
  float* out = (float*)d_out;
  char* ws = (char*)d_ws;

  u16* xT     = (u16*)(ws);              // 33,554,432 B (dead after gemm1; reused as ao)
  u16* q      = (u16*)(ws + 33554432);   // 33,554,432 B
  u16* kv     = (u16*)(ws + 67108864);   //  4,194,304 B
  u16* vT     = (u16*)(ws + 71303168);   //  2,097,152 B
  u16* Wq_b   = (u16*)(ws + 73400320);   //    524,288 B
  u16* Wkv_b  = (u16*)(ws + 73924608);   //  1,572,864 B
  u16* Wout_b = (u16*)(ws + 75497472);   //    524,288 B
  u16* ctx_b  = (u16*)(ws + 76021760);   //  3,145,728 B  (total ~79.2 MB)
  u16* ao     = xT;

  prep_cast<<<dim3(1024), dim3(256), 0, stream>>>(Wq, Wkv, Wout, ctx,
                                                  Wq_b, Wkv_b, Wout_b, ctx_b);
  transpose_x<<<dim3(64, 8, 8), dim3(256), 0, stream>>>(x, xT);
  // q[b][p][e] = sum_c xT[b][p][c] * (Wq*scale)[e][c]
  gemm_nt<0><<<dim3(32, 4, 8), dim3(256), 0, stream>>>(
      xT, Wq_b, (void*)q, 4096, 512, 512, 4096L * 512, 0L, 4096L * 512,
      nullptr, nullptr);
  // kv[bn][e2] = sum_c ctx[bn][c] * Wkv[e2][c]
  gemm_nt<0><<<dim3(16, 8, 1), dim3(256), 0, stream>>>(
      ctx_b, Wkv_b, (void*)kv, 2048, 1024, 768, 0L, 0L, 0L, nullptr, nullptr);
  transpose_v<<<dim3(8, 4, 8), dim3(256), 0, stream>>>(kv, vT);
  attn_kernel<<<dim3(64, 8, 8), dim3(256), 0, stream>>>(q, kv, vT, ao);
  // out[b][c][p] = sum_e Wout[c][e] * ao[b][p][e] + bout[c] + x[b][c][p]
  gemm_nt<1><<<dim3(4, 32, 8), dim3(256), 0, stream>>>(
      Wout_b, ao, (void*)out, 512, 4096, 512, 0L, 4096L * 512, 512L * 4096,
      bout, x);
}

// Round 2
// 165.046 us; speedup vs baseline: 1.5048x; 1.5048x over previous
//
#include <hip/hip_runtime.h>

typedef unsigned short u16;
typedef __bf16 bf16x8 __attribute__((ext_vector_type(8)));
typedef float f32x4 __attribute__((ext_vector_type(4)));

__device__ __forceinline__ u16 f2bf(float f) {
  union { float f; unsigned int u; } v; v.f = f;
  unsigned int r = v.u + 0x7fffu + ((v.u >> 16) & 1u);
  return (u16)(r >> 16);
}

__device__ __forceinline__ f32x4 mfma16(bf16x8 a, bf16x8 b, f32x4 c) {
  return __builtin_amdgcn_mfma_f32_16x16x32_bf16(a, b, c, 0, 0, 0);
}

__device__ __forceinline__ void async16(void* lds, const void* g) {
  __builtin_amdgcn_global_load_lds(
      (const __attribute__((address_space(1))) unsigned int*)g,
      (__attribute__((address_space(3))) unsigned int*)lds, 16, 0, 0);
}

// ---------------------------------------------------------------- prep: casts
__global__ __launch_bounds__(256) void prep_cast(
    const float* __restrict__ Wq, const float* __restrict__ Wkv,
    const float* __restrict__ Wout, const float* __restrict__ ctx,
    u16* __restrict__ Wq_b, u16* __restrict__ Wkv_b,
    u16* __restrict__ Wout_b, u16* __restrict__ ctx_b) {
  const long NWQ = 512L * 512, NWKV = 1024L * 768, NWOUT = 512L * 512, NCTX = 2048L * 768;
  const long total = NWQ + NWKV + NWOUT + NCTX;
  long stride = (long)gridDim.x * 256;
  for (long i = (long)blockIdx.x * 256 + threadIdx.x; i < total; i += stride) {
    long j = i;
    if (j < NWQ) { Wq_b[j] = f2bf(Wq[j] * 0.125f); continue; }
    j -= NWQ;
    if (j < NWKV) { Wkv_b[j] = f2bf(Wkv[j]); continue; }
    j -= NWKV;
    if (j < NWOUT) { Wout_b[j] = f2bf(Wout[j]); continue; }
    j -= NWOUT;
    ctx_b[j] = f2bf(ctx[j]);
  }
}

// ------------------------------------------------- transpose x -> xT bf16
__global__ __launch_bounds__(256) void transpose_x(const float* __restrict__ x,
                                                   u16* __restrict__ xT) {
  __shared__ float tile[64][65];
  const int b = blockIdx.z, p0 = blockIdx.x * 64, c0 = blockIdx.y * 64;
  const int tx = threadIdx.x & 63, ty = threadIdx.x >> 6;
  const float* xb = x + (long)b * (512L * 4096);
  #pragma unroll
  for (int i = ty; i < 64; i += 4)
    tile[i][tx] = xb[(long)(c0 + i) * 4096 + p0 + tx];
  __syncthreads();
  u16* xTb = xT + (long)b * (4096L * 512);
  #pragma unroll
  for (int i = ty; i < 64; i += 4)
    xTb[(long)(p0 + i) * 512 + c0 + tx] = f2bf(tile[tx][i]);
}

// ------------------------------------------------- transpose v -> vT bf16
// kv [2048][1024] bf16 (v = cols 512..1023) -> vT [8][512][256]
__global__ __launch_bounds__(256) void transpose_v(const u16* __restrict__ kv,
                                                   u16* __restrict__ vT) {
  __shared__ u16 tile[64][65];
  const int b = blockIdx.z, e0 = blockIdx.x * 64, n0 = blockIdx.y * 64;
  const int tx = threadIdx.x & 63, ty = threadIdx.x >> 6;
  #pragma unroll
  for (int i = ty; i < 64; i += 4)
    tile[i][tx] = kv[(long)(b * 256 + n0 + i) * 1024 + 512 + e0 + tx];
  __syncthreads();
  #pragma unroll
  for (int i = ty; i < 64; i += 4)
    vT[(long)b * (512L * 256) + (long)(e0 + i) * 256 + n0 + tx] = tile[tx][i];
}

// ---------------------------------------------------------------- NT GEMM
// (unchanged from round 1)
template <int EPI>
__global__ __launch_bounds__(256) void gemm_nt(
    const u16* __restrict__ A, const u16* __restrict__ B, void* __restrict__ Cv,
    int M, int N, int K, long aStrideZ, long bStrideZ, long cStrideZ,
    const float* __restrict__ bias, const float* __restrict__ resid) {
  __shared__ u16 ldsA[2][128 * 32];
  __shared__ u16 ldsB[2][128 * 32];
  const int t = threadIdx.x, wv = t >> 6, ln = t & 63;
  const int m0 = blockIdx.x * 128, n0 = blockIdx.y * 128, z = blockIdx.z;
  const u16* Az = A + (long)z * aStrideZ;
  const u16* Bz = B + (long)z * bStrideZ;
  const int wr = wv >> 1, wc = wv & 1, fr = ln & 15, fq = ln >> 4;

  const u16* aSrc[2];
  const u16* bSrc[2];
  int lbase[2];
  #pragma unroll
  for (int i = 0; i < 2; i++) {
    int c = wv * 64 + ln + i * 256;
    aSrc[i] = Az + (long)(m0 + (c >> 2)) * K + (c & 3) * 8;
    bSrc[i] = Bz + (long)(n0 + (c >> 2)) * K + (c & 3) * 8;
    lbase[i] = (wv * 64 + i * 256) * 8;
  }

  f32x4 acc[4][4] = {};
  const int nk = K >> 5;
  int cur = 0;

  #pragma unroll
  for (int i = 0; i < 2; i++) {
    async16(&ldsA[0][lbase[i]], aSrc[i]);
    async16(&ldsB[0][lbase[i]], bSrc[i]);
  }

  for (int kt = 0; kt < nk; ++kt) {
    __syncthreads();
    if (kt + 1 < nk) {
      const int ko = (kt + 1) * 32;
      #pragma unroll
      for (int i = 0; i < 2; i++) {
        async16(&ldsA[cur ^ 1][lbase[i]], aSrc[i] + ko);
        async16(&ldsB[cur ^ 1][lbase[i]], bSrc[i] + ko);
      }
    }
    bf16x8 a[4], b[4];
    #pragma unroll
    for (int mf = 0; mf < 4; ++mf)
      a[mf] = *(const bf16x8*)&ldsA[cur][(wr * 64 + mf * 16 + fr) * 32 + fq * 8];
    #pragma unroll
    for (int nf = 0; nf < 4; ++nf)
      b[nf] = *(const bf16x8*)&ldsB[cur][(wc * 64 + nf * 16 + fr) * 32 + fq * 8];
    #pragma unroll
    for (int mf = 0; mf < 4; ++mf)
      #pragma unroll
      for (int nf = 0; nf < 4; ++nf)
        acc[mf][nf] = mfma16(a[mf], b[nf], acc[mf][nf]);
    cur ^= 1;
  }

  if (EPI == 0) {
    u16* Cb = (u16*)Cv + (long)z * cStrideZ;
    #pragma unroll
    for (int mf = 0; mf < 4; ++mf)
      #pragma unroll
      for (int r = 0; r < 4; ++r) {
        int grow = m0 + wr * 64 + mf * 16 + fq * 4 + r;
        #pragma unroll
        for (int nf = 0; nf < 4; ++nf) {
          int gcol = n0 + wc * 64 + nf * 16 + fr;
          Cb[(long)grow * N + gcol] = f2bf(acc[mf][nf][r]);
        }
      }
  } else {
    float* Cf = (float*)Cv + (long)z * cStrideZ;
    const float* Rz = resid + (long)z * cStrideZ;
    #pragma unroll
    for (int mf = 0; mf < 4; ++mf)
      #pragma unroll
      for (int r = 0; r < 4; ++r) {
        int grow = m0 + wr * 64 + mf * 16 + fq * 4 + r;
        float bv = bias[grow];
        #pragma unroll
        for (int nf = 0; nf < 4; ++nf) {
          int gcol = n0 + wc * 64 + nf * 16 + fr;
          long idx = (long)grow * N + gcol;
          Cf[idx] = acc[mf][nf][r] + bv + Rz[idx];
        }
      }
  }
}

// ---------------------------------------------------------------- attention
// One block = one (b,h) x 1024 q-rows. K [256][64] and vT [64][256] staged in
// LDS once (XOR-swizzled via pre-swizzled global_load_lds source), then 8
// barrier-free iterations of 128 q-rows across 8 waves (16 rows/wave).
__global__ __launch_bounds__(512) void attn_kernel(
    const u16* __restrict__ q, const u16* __restrict__ kv,
    const u16* __restrict__ vT, u16* __restrict__ ao) {
  __shared__ u16 klds[256 * 64];    // 32 KB  [n][d], byte ^= ((n&7)<<4)
  __shared__ u16 vlds[64 * 256];    // 32 KB  [d][n], byte ^= ((d&7)<<4)
  __shared__ u16 plds[128 * 256];   // 64 KB  [p][n], byte ^= ((p&7)<<4)
  const int t = threadIdx.x, w = t >> 6, ln = t & 63;
  const int fr = ln & 15, fq = ln >> 4;
  const int p0 = blockIdx.x * 1024, h = blockIdx.y, b = blockIdx.z;

  const u16* kb = kv + (long)b * 256 * 1024 + h * 64;            // row stride 1024
  const u16* vb = vT + (long)b * (512L * 256) + (long)h * 64 * 256;  // row stride 256

  // ---- stage K: 2048 chunks of 16B; lane chunk = cbase + ln, row = chunk>>3
  #pragma unroll
  for (int i = 0; i < 4; ++i) {
    int cbase = i * 512 + w * 64;          // wave-uniform
    int chunk = cbase + ln;
    int row = chunk >> 3, slot = chunk & 7;
    async16(&klds[cbase * 8], kb + (long)row * 1024 + ((slot ^ (row & 7)) << 3));
  }
  // ---- stage V: 2048 chunks; row = chunk>>5 (32 slots/row)
  #pragma unroll
  for (int i = 0; i < 4; ++i) {
    int cbase = i * 512 + w * 64;
    int chunk = cbase + ln;
    int row = chunk >> 5, slot = chunk & 31;
    async16(&vlds[cbase * 8], vb + (long)row * 256 + ((slot ^ (row & 7)) << 3));
  }
  __syncthreads();  // drains vmcnt before barrier

  const char* kraw = (const char*)klds;
  const char* vraw = (const char*)vlds;
  char* praw = (char*)plds;

  for (int it = 0; it < 8; ++it) {
    const int qrow = p0 + it * 128 + w * 16;   // this wave's 16 rows

    // Q fragments (A-operand): row = qrow + fr
    const u16* qb = q + ((long)b * 4096 + qrow + fr) * 512 + h * 64;
    bf16x8 qf[2];
    #pragma unroll
    for (int kk = 0; kk < 2; ++kk)
      qf[kk] = *(const bf16x8*)&qb[kk * 32 + fq * 8];

    // S = Q.K^T from swizzled klds
    f32x4 s[16] = {};
    #pragma unroll
    for (int nf = 0; nf < 16; ++nf) {
      int row = nf * 16 + fr;
      #pragma unroll
      for (int kk = 0; kk < 2; ++kk) {
        bf16x8 kf = *(const bf16x8*)(kraw + row * 128 +
                                     ((kk * 64 + fq * 16) ^ ((row & 7) << 4)));
        s[nf] = mfma16(qf[kk], kf, s[nf]);
      }
    }

    // softmax per row (row spread over the 16-lane column group)
    #pragma unroll
    for (int r = 0; r < 4; ++r) {
      float m = -3.0e38f;
      #pragma unroll
      for (int nf = 0; nf < 16; ++nf) m = fmaxf(m, s[nf][r]);
      m = fmaxf(m, __shfl_xor(m, 1));
      m = fmaxf(m, __shfl_xor(m, 2));
      m = fmaxf(m, __shfl_xor(m, 4));
      m = fmaxf(m, __shfl_xor(m, 8));
      float sum = 0.f;
      #pragma unroll
      for (int nf = 0; nf < 16; ++nf) {
        float e = __expf(s[nf][r] - m);
        s[nf][r] = e;
        sum += e;
      }
      sum += __shfl_xor(sum, 1);
      sum += __shfl_xor(sum, 2);
      sum += __shfl_xor(sum, 4);
      sum += __shfl_xor(sum, 8);
      float inv = 1.0f / sum;
      int prow = w * 16 + fq * 4 + r;
      #pragma unroll
      for (int nf = 0; nf < 16; ++nf) {
        int pcol = nf * 16 + fr;
        *(u16*)(praw + prow * 512 + ((pcol * 2) ^ ((prow & 7) << 4))) =
            f2bf(s[nf][r] * inv);
      }
    }
    asm volatile("s_waitcnt lgkmcnt(0)" ::: "memory");  // same-wave P w->r

    // O = P.V from swizzled plds / vlds
    f32x4 o[4] = {};
    const int prowA = w * 16 + fr;
    #pragma unroll
    for (int kk2 = 0; kk2 < 8; ++kk2) {
      bf16x8 pf = *(const bf16x8*)(praw + prowA * 512 +
                                   ((kk2 * 64 + fq * 16) ^ ((prowA & 7) << 4)));
      #pragma unroll
      for (int nfd = 0; nfd < 4; ++nfd) {
        int dd = nfd * 16 + fr;
        bf16x8 vf = *(const bf16x8*)(vraw + dd * 512 +
                                     ((kk2 * 64 + fq * 16) ^ ((dd & 7) << 4)));
        o[nfd] = mfma16(pf, vf, o[nfd]);
      }
    }

    u16* aob = ao + ((long)b * 4096 + qrow) * 512 + h * 64;
    #pragma unroll
    for (int nfd = 0; nfd < 4; ++nfd)
      #pragma unroll
      for (int r = 0; r < 4; ++r)
        aob[(long)(fq * 4 + r) * 512 + nfd * 16 + fr] = f2bf(o[nfd][r]);
  }
}

// ---------------------------------------------------------------- launch
extern "C" void kernel_launch(void* const* d_in, const int* in_sizes, int n_in,
                              void* d_out, int out_size, void* d_ws, size_t ws_size,
                              hipStream_t stream) {
  const float* x    = (const float*)d_in[0];
  const float* ctx  = (const float*)d_in[1];
  const float* Wq   = (const float*)d_in[2];
  const float* Wkv  = (const float*)d_in[3];
  const float* Wout = (const float*)d_in[4];
  const float* bout = (const float*)d_in[5];
  float* out = (float*)d_out;
  char* ws = (char*)d_ws;

  u16* xT     = (u16*)(ws);              // 33,554,432 B (reused as ao)
  u16* q      = (u16*)(ws + 33554432);   // 33,554,432 B
  u16* kv     = (u16*)(ws + 67108864);   //  4,194,304 B
  u16* vT     = (u16*)(ws + 71303168);   //  2,097,152 B
  u16* Wq_b   = (u16*)(ws + 73400320);   //    524,288 B
  u16* Wkv_b  = (u16*)(ws + 73924608);   //  1,572,864 B
  u16* Wout_b = (u16*)(ws + 75497472);   //    524,288 B
  u16* ctx_b  = (u16*)(ws + 76021760);   //  3,145,728 B
  u16* ao     = xT;

  prep_cast<<<dim3(1024), dim3(256), 0, stream>>>(Wq, Wkv, Wout, ctx,
                                                  Wq_b, Wkv_b, Wout_b, ctx_b);
  transpose_x<<<dim3(64, 8, 8), dim3(256), 0, stream>>>(x, xT);
  gemm_nt<0><<<dim3(32, 4, 8), dim3(256), 0, stream>>>(
      xT, Wq_b, (void*)q, 4096, 512, 512, 4096L * 512, 0L, 4096L * 512,
      nullptr, nullptr);
  gemm_nt<0><<<dim3(16, 8, 1), dim3(256), 0, stream>>>(
      ctx_b, Wkv_b, (void*)kv, 2048, 1024, 768, 0L, 0L, 0L, nullptr, nullptr);
  transpose_v<<<dim3(8, 4, 8), dim3(256), 0, stream>>>(kv, vT);
  attn_kernel<<<dim3(4, 8, 8), dim3(512), 0, stream>>>(q, kv, vT, ao);
  gemm_nt<1><<<dim3(4, 32, 8), dim3(256), 0, stream>>>(
      Wout_b, ao, (void*)out, 512, 4096, 512, 0L, 4096L * 512, 512L * 4096,
      bout, x);
}

// Round 3
// 152.471 us; speedup vs baseline: 1.6289x; 1.0825x over previous
//
#include <hip/hip_runtime.h>

typedef unsigned short u16;
typedef __bf16 bf16x8 __attribute__((ext_vector_type(8)));
typedef __bf16 bf16x4 __attribute__((ext_vector_type(4)));
typedef float f32x4 __attribute__((ext_vector_type(4)));

__device__ __forceinline__ u16 f2bf(float f) {
  __bf16 h = (__bf16)f;
  return *(u16*)&h;
}

__device__ __forceinline__ f32x4 mfma16(bf16x8 a, bf16x8 b, f32x4 c) {
  return __builtin_amdgcn_mfma_f32_16x16x32_bf16(a, b, c, 0, 0, 0);
}

__device__ __forceinline__ void async16(void* lds, const void* g) {
  __builtin_amdgcn_global_load_lds(
      (const __attribute__((address_space(1))) unsigned int*)g,
      (__attribute__((address_space(3))) unsigned int*)lds, 16, 0, 0);
}

// fold softmax scale AND log2(e) into Wq so softmax uses raw v_exp_f32 (exp2)
#define QSCALE 0.18033688011112042f  // 0.125 * log2(e)

// ---------------------------------------------------------------- prep: casts
__global__ __launch_bounds__(256) void prep_cast(
    const float* __restrict__ Wq, const float* __restrict__ Wkv,
    const float* __restrict__ Wout, const float* __restrict__ ctx,
    u16* __restrict__ Wq_b, u16* __restrict__ Wkv_b,
    u16* __restrict__ Wout_b, u16* __restrict__ ctx_b) {
  const long NWQ = 512L * 512, NWKV = 1024L * 768, NWOUT = 512L * 512, NCTX = 2048L * 768;
  const long total = NWQ + NWKV + NWOUT + NCTX;
  long stride = (long)gridDim.x * 256;
  for (long i = (long)blockIdx.x * 256 + threadIdx.x; i < total; i += stride) {
    long j = i;
    if (j < NWQ) { Wq_b[j] = f2bf(Wq[j] * QSCALE); continue; }
    j -= NWQ;
    if (j < NWKV) { Wkv_b[j] = f2bf(Wkv[j]); continue; }
    j -= NWKV;
    if (j < NWOUT) { Wout_b[j] = f2bf(Wout[j]); continue; }
    j -= NWOUT;
    ctx_b[j] = f2bf(ctx[j]);
  }
}

// ------------------------------------------------- transpose x -> xT bf16
__global__ __launch_bounds__(256) void transpose_x(const float* __restrict__ x,
                                                   u16* __restrict__ xT) {
  __shared__ float tile[64][65];
  const int b = blockIdx.z, p0 = blockIdx.x * 64, c0 = blockIdx.y * 64;
  const int tx = threadIdx.x & 63, ty = threadIdx.x >> 6;
  const float* xb = x + (long)b * (512L * 4096);
  #pragma unroll
  for (int i = ty; i < 64; i += 4)
    tile[i][tx] = xb[(long)(c0 + i) * 4096 + p0 + tx];
  __syncthreads();
  u16* xTb = xT + (long)b * (4096L * 512);
  #pragma unroll
  for (int i = ty; i < 64; i += 4)
    xTb[(long)(p0 + i) * 512 + c0 + tx] = f2bf(tile[tx][i]);
}

// ------------------------------------------------- transpose v -> vT bf16
__global__ __launch_bounds__(256) void transpose_v(const u16* __restrict__ kv,
                                                   u16* __restrict__ vT) {
  __shared__ u16 tile[64][65];
  const int b = blockIdx.z, e0 = blockIdx.x * 64, n0 = blockIdx.y * 64;
  const int tx = threadIdx.x & 63, ty = threadIdx.x >> 6;
  #pragma unroll
  for (int i = ty; i < 64; i += 4)
    tile[i][tx] = kv[(long)(b * 256 + n0 + i) * 1024 + 512 + e0 + tx];
  __syncthreads();
  #pragma unroll
  for (int i = ty; i < 64; i += 4)
    vT[(long)b * (512L * 256) + (long)(e0 + i) * 256 + n0 + tx] = tile[tx][i];
}

// ---------------------------------------------------------------- NT GEMM
// C[M][N] = A[M][K] . B[N][K]^T. 128x128 tile, BK=32, double-buffered
// global_load_lds. LDS XOR swizzle: byte ^= ((row>>1)&3)<<4 (inverse-swizzled
// source + swizzled read -> 2-way bank access, free).
template <int EPI>
__global__ __launch_bounds__(256) void gemm_nt(
    const u16* __restrict__ A, const u16* __restrict__ B, void* __restrict__ Cv,
    int M, int N, int K, long aStrideZ, long bStrideZ, long cStrideZ,
    const float* __restrict__ bias, const float* __restrict__ resid) {
  __shared__ u16 ldsA[2][128 * 32];
  __shared__ u16 ldsB[2][128 * 32];
  const int t = threadIdx.x, wv = t >> 6, ln = t & 63;
  const int m0 = blockIdx.x * 128, n0 = blockIdx.y * 128, z = blockIdx.z;
  const u16* Az = A + (long)z * aStrideZ;
  const u16* Bz = B + (long)z * bStrideZ;
  const int wr = wv >> 1, wc = wv & 1, fr = ln & 15, fq = ln >> 4;

  const u16* aSrc[2];
  const u16* bSrc[2];
  int lbase[2];
  #pragma unroll
  for (int i = 0; i < 2; i++) {
    int c = wv * 64 + ln + i * 256;
    int row = c >> 2, slot = (c & 3) ^ ((c >> 3) & 3);  // inverse swizzle
    aSrc[i] = Az + (long)(m0 + row) * K + slot * 8;
    bSrc[i] = Bz + (long)(n0 + row) * K + slot * 8;
    lbase[i] = (wv * 64 + i * 256) * 8;
  }

  f32x4 acc[4][4] = {};
  const int nk = K >> 5;
  int cur = 0;

  #pragma unroll
  for (int i = 0; i < 2; i++) {
    async16(&ldsA[0][lbase[i]], aSrc[i]);
    async16(&ldsB[0][lbase[i]], bSrc[i]);
  }

  const int swzg = (fr >> 1) & 3;  // row bits 1-2 (row = ...16*mf + fr)
  for (int kt = 0; kt < nk; ++kt) {
    __syncthreads();
    if (kt + 1 < nk) {
      const int ko = (kt + 1) * 32;
      #pragma unroll
      for (int i = 0; i < 2; i++) {
        async16(&ldsA[cur ^ 1][lbase[i]], aSrc[i] + ko);
        async16(&ldsB[cur ^ 1][lbase[i]], bSrc[i] + ko);
      }
    }
    const char* Ab = (const char*)ldsA[cur];
    const char* Bb = (const char*)ldsB[cur];
    bf16x8 a[4], b[4];
    #pragma unroll
    for (int mf = 0; mf < 4; ++mf)
      a[mf] = *(const bf16x8*)(Ab + (wr * 64 + mf * 16 + fr) * 64 + ((fq ^ swzg) * 16));
    #pragma unroll
    for (int nf = 0; nf < 4; ++nf)
      b[nf] = *(const bf16x8*)(Bb + (wc * 64 + nf * 16 + fr) * 64 + ((fq ^ swzg) * 16));
    #pragma unroll
    for (int mf = 0; mf < 4; ++mf)
      #pragma unroll
      for (int nf = 0; nf < 4; ++nf)
        acc[mf][nf] = mfma16(a[mf], b[nf], acc[mf][nf]);
    cur ^= 1;
  }

  if (EPI == 0) {
    u16* Cb = (u16*)Cv + (long)z * cStrideZ;
    #pragma unroll
    for (int mf = 0; mf < 4; ++mf)
      #pragma unroll
      for (int r = 0; r < 4; ++r) {
        int grow = m0 + wr * 64 + mf * 16 + fq * 4 + r;
        #pragma unroll
        for (int nf = 0; nf < 4; ++nf) {
          int gcol = n0 + wc * 64 + nf * 16 + fr;
          Cb[(long)grow * N + gcol] = f2bf(acc[mf][nf][r]);
        }
      }
  } else {
    float* Cf = (float*)Cv + (long)z * cStrideZ;
    const float* Rz = resid + (long)z * cStrideZ;
    #pragma unroll
    for (int mf = 0; mf < 4; ++mf)
      #pragma unroll
      for (int r = 0; r < 4; ++r) {
        int grow = m0 + wr * 64 + mf * 16 + fq * 4 + r;
        float bv = bias[grow];
        #pragma unroll
        for (int nf = 0; nf < 4; ++nf) {
          int gcol = n0 + wc * 64 + nf * 16 + fr;
          long idx = (long)grow * N + gcol;
          Cf[idx] = acc[mf][nf][r] + bv + Rz[idx];
        }
      }
  }
}

// ---------------------------------------------------------------- attention
// Swapped-QK structure: s = mfma(K, Q) so lane (fq,fr) holds
// P[n = nb*16+fq*4+r][p = qrow+fr].  Softmax: 64 lane-local values + 2
// shuffles (xor 16, 32).  P stored unnormalized as 16 packed ds_write_b64;
// PV = mfma(V, P) puts O lanes on p too -> 1/sum folded into O (lane-local),
// packed 8B ao stores.  K/V staged once in swizzled LDS; no barriers in loop.
__global__ __launch_bounds__(512) void attn_kernel(
    const u16* __restrict__ q, const u16* __restrict__ kv,
    const u16* __restrict__ vT, u16* __restrict__ ao) {
  __shared__ u16 klds[256 * 64];    // [n][d] rows 128B, byte ^= ((n&7)<<4)
  __shared__ u16 vlds[64 * 256];    // [d][n] rows 512B, byte ^= ((d&7)<<4)
  __shared__ u16 plds[128 * 256];   // [p][n] rows 512B, byte ^= ((p&7)<<4)
  const int t = threadIdx.x, w = t >> 6, ln = t & 63;
  const int fr = ln & 15, fq = ln >> 4;
  const int p0 = blockIdx.x * 1024, h = blockIdx.y, b = blockIdx.z;

  const u16* kb = kv + (long)b * 256 * 1024 + h * 64;
  const u16* vb = vT + (long)b * (512L * 256) + (long)h * 64 * 256;

  #pragma unroll
  for (int i = 0; i < 4; ++i) {
    int cbase = i * 512 + w * 64;
    int chunk = cbase + ln;
    int row = chunk >> 3, slot = chunk & 7;
    async16(&klds[cbase * 8], kb + (long)row * 1024 + ((slot ^ (row & 7)) << 3));
  }
  #pragma unroll
  for (int i = 0; i < 4; ++i) {
    int cbase = i * 512 + w * 64;
    int chunk = cbase + ln;
    int row = chunk >> 5, slot = chunk & 31;
    async16(&vlds[cbase * 8], vb + (long)row * 256 + ((slot ^ (row & 7)) << 3));
  }
  __syncthreads();

  const char* kraw = (const char*)klds;
  const char* vraw = (const char*)vlds;
  char* praw = (char*)plds;
  const int prowL = w * 16 + fr;       // this lane's private P row in LDS
  const int swz = (fr & 7) << 4;       // same for K rows (nb*16+fr) & V rows

  const u16* qbase = q + ((long)b * 4096 + p0 + w * 16 + fr) * 512 + h * 64;
  bf16x8 qf0 = *(const bf16x8*)&qbase[fq * 8];
  bf16x8 qf1 = *(const bf16x8*)&qbase[32 + fq * 8];

  for (int it = 0; it < 8; ++it) {
    // ---- S^T = K . Q^T : lane holds P[nb*16+fq*4+r][p=fr]
    f32x4 s[16] = {};
    #pragma unroll
    for (int nb = 0; nb < 16; ++nb) {
      int n = nb * 16 + fr;
      bf16x8 kf0 = *(const bf16x8*)(kraw + n * 128 + ((fq * 16) ^ swz));
      bf16x8 kf1 = *(const bf16x8*)(kraw + n * 128 + ((64 + fq * 16) ^ swz));
      s[nb] = mfma16(kf0, qf0, s[nb]);
      s[nb] = mfma16(kf1, qf1, s[nb]);
    }

    // ---- prefetch next Q during softmax
    const u16* qn = qbase + (long)(((it + 1) & 7) * 128) * 512;
    bf16x8 qn0 = *(const bf16x8*)&qn[fq * 8];
    bf16x8 qn1 = *(const bf16x8*)&qn[32 + fq * 8];

    // ---- softmax for row p=fr: local over 64 values + shfl 16/32
    f32x4 mx = s[0];
    #pragma unroll
    for (int nb = 1; nb < 16; ++nb) {
      mx[0] = fmaxf(mx[0], s[nb][0]); mx[1] = fmaxf(mx[1], s[nb][1]);
      mx[2] = fmaxf(mx[2], s[nb][2]); mx[3] = fmaxf(mx[3], s[nb][3]);
    }
    float m = fmaxf(fmaxf(mx[0], mx[1]), fmaxf(mx[2], mx[3]));
    m = fmaxf(m, __shfl_xor(m, 16));
    m = fmaxf(m, __shfl_xor(m, 32));
    f32x4 sm = {0.f, 0.f, 0.f, 0.f};
    #pragma unroll
    for (int nb = 0; nb < 16; ++nb) {
      #pragma unroll
      for (int r = 0; r < 4; ++r)
        s[nb][r] = __builtin_amdgcn_exp2f(s[nb][r] - m);
      sm += s[nb];
    }
    float sum = (sm[0] + sm[1]) + (sm[2] + sm[3]);
    sum += __shfl_xor(sum, 16);
    sum += __shfl_xor(sum, 32);
    float inv = 1.0f / sum;

    // ---- P write: unnormalized, 16x packed 8B (2-way banks, free)
    #pragma unroll
    for (int nb = 0; nb < 16; ++nb) {
      bf16x4 pk;
      #pragma unroll
      for (int r = 0; r < 4; ++r) pk[r] = (__bf16)s[nb][r];
      *(bf16x4*)(praw + prowL * 512 + ((nb * 32 + fq * 8) ^ swz)) = pk;
    }
    asm volatile("s_waitcnt lgkmcnt(0)" ::: "memory");
    __builtin_amdgcn_sched_barrier(0);

    // ---- O^T = V^T . P^T : lane holds O[p=fr][d = nfd*16+fq*4+r]
    f32x4 o[4] = {};
    #pragma unroll
    for (int kk2 = 0; kk2 < 8; ++kk2) {
      bf16x8 pf = *(const bf16x8*)(praw + prowL * 512 + ((kk2 * 64 + fq * 16) ^ swz));
      #pragma unroll
      for (int nfd = 0; nfd < 4; ++nfd) {
        bf16x8 vf = *(const bf16x8*)(vraw + (nfd * 16 + fr) * 512 +
                                     ((kk2 * 64 + fq * 16) ^ swz));
        o[nfd] = mfma16(vf, pf, o[nfd]);
      }
    }

    // ---- scaled packed store: lane p = fr, 4x 8B
    u16* aob = ao + ((long)b * 4096 + p0 + it * 128 + w * 16 + fr) * 512 + h * 64;
    #pragma unroll
    for (int nfd = 0; nfd < 4; ++nfd) {
      bf16x4 ov;
      #pragma unroll
      for (int r = 0; r < 4; ++r) ov[r] = (__bf16)(o[nfd][r] * inv);
      *(bf16x4*)(aob + nfd * 16 + fq * 4) = ov;
    }
    qf0 = qn0;
    qf1 = qn1;
  }
}

// ---------------------------------------------------------------- launch
extern "C" void kernel_launch(void* const* d_in, const int* in_sizes, int n_in,
                              void* d_out, int out_size, void* d_ws, size_t ws_size,
                              hipStream_t stream) {
  const float* x    = (const float*)d_in[0];
  const float* ctx  = (const float*)d_in[1];
  const float* Wq   = (const float*)d_in[2];
  const float* Wkv  = (const float*)d_in[3];
  const float* Wout = (const float*)d_in[4];
  const float* bout = (const float*)d_in[5];
  float* out = (float*)d_out;
  char* ws = (char*)d_ws;

  u16* xT     = (u16*)(ws);              // 33,554,432 B (reused as ao)
  u16* q      = (u16*)(ws + 33554432);   // 33,554,432 B
  u16* kv     = (u16*)(ws + 67108864);   //  4,194,304 B
  u16* vT     = (u16*)(ws + 71303168);   //  2,097,152 B
  u16* Wq_b   = (u16*)(ws + 73400320);   //    524,288 B
  u16* Wkv_b  = (u16*)(ws + 73924608);   //  1,572,864 B
  u16* Wout_b = (u16*)(ws + 75497472);   //    524,288 B
  u16* ctx_b  = (u16*)(ws + 76021760);   //  3,145,728 B
  u16* ao     = xT;

  prep_cast<<<dim3(1024), dim3(256), 0, stream>>>(Wq, Wkv, Wout, ctx,
                                                  Wq_b, Wkv_b, Wout_b, ctx_b);
  transpose_x<<<dim3(64, 8, 8), dim3(256), 0, stream>>>(x, xT);
  gemm_nt<0><<<dim3(32, 4, 8), dim3(256), 0, stream>>>(
      xT, Wq_b, (void*)q, 4096, 512, 512, 4096L * 512, 0L, 4096L * 512,
      nullptr, nullptr);
  gemm_nt<0><<<dim3(16, 8, 1), dim3(256), 0, stream>>>(
      ctx_b, Wkv_b, (void*)kv, 2048, 1024, 768, 0L, 0L, 0L, nullptr, nullptr);
  transpose_v<<<dim3(8, 4, 8), dim3(256), 0, stream>>>(kv, vT);
  attn_kernel<<<dim3(4, 8, 8), dim3(512), 0, stream>>>(q, kv, vT, ao);
  gemm_nt<1><<<dim3(4, 32, 8), dim3(256), 0, stream>>>(
      Wout_b, ao, (void*)out, 512, 4096, 512, 0L, 4096L * 512, 512L * 4096,
      bout, x);
}